// Round 5
// baseline (551.078 us; speedup 1.0000x reference)
//
#include <hip/hip_runtime.h>
#include <math.h>

#define BB   2
#define LL   2048
#define HIDD 2048
#define NHH  16
#define HDD  128
#define QKVN 6144   // 3*HIDD
#define NTASK 34    // KV-split tasks per (b,h)
#define PSTRIDE 33792  // 32KB partial O + 512B m + 512B l
#define THR2 11.5416f  // defer-max threshold, log2 domain (= 8 nats)

typedef unsigned short u16;
typedef float  f32x4 __attribute__((ext_vector_type(4)));
typedef __bf16 bf16x8 __attribute__((ext_vector_type(8)));

static __device__ __forceinline__ float exp2_fast(float x){
  return __builtin_amdgcn_exp2f(x);    // v_exp_f32 (native 2^x)
}
static __device__ __forceinline__ u16 f2bf(float x){
  unsigned u = __float_as_uint(x);
  return (u16)((u + 0x7fffu + ((u >> 16) & 1u)) >> 16);
}
static __device__ __forceinline__ float bf2f(u16 b){
  return __uint_as_float(((unsigned)b) << 16);
}
static __device__ __forceinline__ void gl_lds16(const void* g, void* l){
  __builtin_amdgcn_global_load_lds(
      (__attribute__((address_space(1))) void*)(void*)g,
      (__attribute__((address_space(3))) void*)l,
      16, 0, 0);
}

// ---------------- prep kernels ----------------

__global__ void cvt_f32_bf16_k(const float* __restrict__ src, u16* __restrict__ dst, int n4){
  int i = blockIdx.x * blockDim.x + threadIdx.x;
  if (i >= n4) return;
  float4 v = ((const float4*)src)[i];
  ushort4 o;
  o.x = f2bf(v.x); o.y = f2bf(v.y); o.z = f2bf(v.z); o.w = f2bf(v.w);
  ((ushort4*)dst)[i] = o;
}

// src: R x C f32 (row-major) -> dst: C x R bf16
__global__ void transpose_cvt_k(const float* __restrict__ src, u16* __restrict__ dst, int R, int C){
  __shared__ float t[32][33];
  int c0 = blockIdx.x * 32, r0 = blockIdx.y * 32;
  int tx = threadIdx.x, ty = threadIdx.y;
  #pragma unroll
  for (int i = 0; i < 32; i += 8) t[ty + i][tx] = src[(size_t)(r0 + ty + i) * C + c0 + tx];
  __syncthreads();
  #pragma unroll
  for (int i = 0; i < 32; i += 8) dst[(size_t)(c0 + ty + i) * R + r0 + tx] = f2bf(t[tx][ty + i]);
}

// in-place RoPE on q,k sections of qkv (bf16). idx over B*L*NH*64
// Q additionally pre-scaled by 1/sqrt(128)*log2(e) so attention scores are
// directly in exp2 domain.
__global__ void rope_k(u16* __restrict__ qkv){
  int idx = blockIdx.x * blockDim.x + threadIdx.x;
  int d   = idx & 63;
  int h   = (idx >> 6) & 15;
  int row = idx >> 10;           // b*L + l
  int l   = row & (LL - 1);
  float fr = __expf(-(float)d * 0.17988946f);   // ln(1e5)/64
  float th = (float)l * 0.25f * fr;             // pos/ROPE_SCALE * freq
  float s, c;
  sincosf(th, &s, &c);
  size_t base = (size_t)row * QKVN + h * HDD + d;
  #pragma unroll
  for (int part = 0; part < 2; part++){         // q then k
    float f = (part == 0) ? 0.12753375f : 1.0f; // scale*log2e folded into Q
    float x1 = bf2f(qkv[base]), x2 = bf2f(qkv[base + 64]);
    qkv[base]      = f2bf((x1 * c - x2 * s) * f);
    qkv[base + 64] = f2bf((x1 * s + x2 * c) * f);
    base += HIDD;
  }
}

// v section of qkv -> vt[(b,h), d, l]
__global__ void build_vt_k(const u16* __restrict__ qkv, u16* __restrict__ vt){
  __shared__ u16 t[32][33];
  int bh = blockIdx.z;
  int b = bh >> 4, h = bh & 15;
  const u16* src = qkv + (size_t)b * LL * QKVN + 2 * HIDD + h * HDD; // [l][d] stride QKVN
  u16* dst = vt + (size_t)bh * HDD * LL;                              // [d][l] stride LL
  int d0 = blockIdx.x * 32, l0 = blockIdx.y * 32;
  int tx = threadIdx.x, ty = threadIdx.y;
  #pragma unroll
  for (int i = 0; i < 32; i += 8) t[ty + i][tx] = src[(size_t)(l0 + ty + i) * QKVN + d0 + tx];
  __syncthreads();
  #pragma unroll
  for (int i = 0; i < 32; i += 8) dst[(size_t)(d0 + ty + i) * LL + l0 + tx] = t[tx][ty + i];
}

// ---------------- GEMM: C[M,N] = A[M,K] * Bt[N,K]^T  (bf16 in, f32 acc) ----------------

template<int OUT_BF16>
__global__ __launch_bounds__(256) void gemm_bt_k(
    const u16* __restrict__ A, const u16* __restrict__ Bt,
    void* __restrict__ Cout, int M, int N, int K)
{
  __shared__ __align__(16) u16 As[128 * 64];
  __shared__ __align__(16) u16 Bs[128 * 64];
  const int tid = threadIdx.x, lane = tid & 63, wv = tid >> 6;
  const int wr = wv >> 1, wc = wv & 1;
  const int m0 = blockIdx.y * 128, n0 = blockIdx.x * 128;
  const int rq = lane >> 4, cl = lane & 15;

  const f32x4 Z = {0.f, 0.f, 0.f, 0.f};
  f32x4 acc[4][4];
  #pragma unroll
  for (int m = 0; m < 4; m++)
    #pragma unroll
    for (int n = 0; n < 4; n++) acc[m][n] = Z;

  for (int kt = 0; kt < K; kt += 64){
    #pragma unroll
    for (int i = 0; i < 4; i++){
      int fb = (i * 4 + wv) * 64;          // wave-uniform 16B-chunk base
      int p  = (fb + lane) * 16;           // this lane's physical LDS byte
      int r  = p >> 7;                     // tile row (128B rows)
      int cbs = (p & 127) ^ ((r & 7) << 4);
      gl_lds16(A  + (size_t)(m0 + r) * K + kt + (cbs >> 1), &As[fb * 8]);
      gl_lds16(Bt + (size_t)(n0 + r) * K + kt + (cbs >> 1), &Bs[fb * 8]);
    }
    __syncthreads();
    #pragma unroll
    for (int ks = 0; ks < 2; ks++){
      const int kb = ks * 64 + rq * 16;    // k byte offset in row
      bf16x8 a[4], b[4];
      #pragma unroll
      for (int m = 0; m < 4; m++){
        int r = wr * 64 + m * 16 + cl;
        a[m] = *(const bf16x8*)((const char*)As + r * 128 + (kb ^ ((r & 7) << 4)));
      }
      #pragma unroll
      for (int n = 0; n < 4; n++){
        int r = wc * 64 + n * 16 + cl;
        b[n] = *(const bf16x8*)((const char*)Bs + r * 128 + (kb ^ ((r & 7) << 4)));
      }
      #pragma unroll
      for (int m = 0; m < 4; m++)
        #pragma unroll
        for (int n = 0; n < 4; n++)
          acc[m][n] = __builtin_amdgcn_mfma_f32_16x16x32_bf16(a[m], b[n], acc[m][n], 0, 0, 0);
    }
    __syncthreads();
  }

  #pragma unroll
  for (int m = 0; m < 4; m++){
    int gr0 = m0 + wr * 64 + m * 16 + rq * 4;
    #pragma unroll
    for (int n = 0; n < 4; n++){
      int gc = n0 + wc * 64 + n * 16 + cl;
      #pragma unroll
      for (int rr = 0; rr < 4; rr++){
        if (OUT_BF16) ((u16*)Cout)[(size_t)(gr0 + rr) * N + gc] = f2bf(acc[m][n][rr]);
        else          ((float*)Cout)[(size_t)(gr0 + rr) * N + gc] = acc[m][n][rr];
      }
    }
  }
}

// ---------------- flash attention, KV-split, staged K/V, lean softmax ----------------
// Task x in [0,34): balanced KV-chunk of q-tile qt (128 rows). 4 waves x 32 q-rows.
// K double-buffered in LDS; V single-buffered; P reuses the consumed K buffer.
// Row-sum via ones-column MFMA; per-tile max via lane-local gate (defer-max THR).
// LDS = 48KB -> 3 blocks/CU.

#define STAGE_K(jj, bsel) do {                                                            \
  const int kv0_ = (jj) * 64;                                                             \
  _Pragma("unroll")                                                                       \
  for (int i_ = 0; i_ < 4; i_++){                                                         \
    int fb_ = (i_ * 4 + wv) * 64;                                                         \
    int p_  = (fb_ + lane) * 16;                                                          \
    int r_ = p_ >> 8; int cb_ = (p_ & 255) ^ ((r_ & 7) << 4);                             \
    gl_lds16(qkv + (size_t)(b * LL + kv0_ + r_) * QKVN + HIDD + h * HDD + (cb_ >> 1),     \
             &Kb[bsel][fb_ * 8]);                                                         \
  }                                                                                       \
} while(0)

#define STAGE_V(jj) do {                                                                  \
  const int kv0_ = (jj) * 64;                                                             \
  _Pragma("unroll")                                                                       \
  for (int i_ = 0; i_ < 4; i_++){                                                         \
    int fb_ = (i_ * 4 + wv) * 64;                                                         \
    int p_  = (fb_ + lane) * 16;                                                          \
    int r_ = p_ >> 7; int cb_ = (p_ & 127) ^ ((r_ & 7) << 4);                             \
    gl_lds16(vt + (size_t)(bh * HDD + r_) * LL + kv0_ + (cb_ >> 1), &Vs[fb_ * 8]);        \
  }                                                                                       \
} while(0)

__global__ __launch_bounds__(256, 3) void attn_split_k(
    const u16* __restrict__ qkv, const u16* __restrict__ vt,
    char* __restrict__ part)
{
  __shared__ __align__(16) u16 Kb[2][64 * 128];   // K tiles [64][128], 2x16KB
  __shared__ __align__(16) u16 Vs[128 * 64];      // V^T tile [128][64], 16KB
  const int tid = threadIdx.x, lane = tid & 63, wv = tid >> 6;
  const int x  = (NTASK - 1) - (int)blockIdx.x;   // big tasks dispatch first
  const int bh = blockIdx.y;
  const int b = bh >> 4, h = bh & 15;
  const int rq = lane >> 4, cl = lane & 15;

  int qt, s, nsp;
  if      (x <  5) { qt = x;                 s = 0;           nsp = 1; }
  else if (x < 15) { qt = 5 + ((x-5) >> 1);  s = (x-5) & 1;   nsp = 2; }
  else if (x < 30) { qt = 10 + (x-15)/3;     s = (x-15)%3;    nsp = 3; }
  else             { qt = 15;                s = x - 30;      nsp = 4; }
  const int T    = 2 * (qt + 1);
  const int base = T / nsp, rem = T % nsp;
  const int j0   = s * base + (s < rem ? s : rem);
  const int jend = j0 + base + (s < rem ? 1 : 0);

  // Q fragments (already scaled by 1/sqrt(d)*log2e in rope_k)
  bf16x8 qf[2][4];
  #pragma unroll
  for (int rt = 0; rt < 2; rt++){
    const u16* qb = qkv + (size_t)(b * LL + qt * 128 + wv * 32 + rt * 16 + cl) * QKVN + h * HDD + rq * 8;
    #pragma unroll
    for (int ks = 0; ks < 4; ks++) qf[rt][ks] = *(const bf16x8*)(qb + ks * 32);
  }

  bf16x8 ones;
  #pragma unroll
  for (int i = 0; i < 8; i++) ones[i] = (__bf16)1.0f;

  const f32x4 Z = {0.f, 0.f, 0.f, 0.f};
  f32x4 acco[2][8];
  f32x4 accl[2];                 // row-sum accumulator (ones-column MFMA)
  float mst[2][4];
  #pragma unroll
  for (int rt = 0; rt < 2; rt++){
    #pragma unroll
    for (int n = 0; n < 8; n++) acco[rt][n] = Z;
    accl[rt] = Z;
    #pragma unroll
    for (int rr = 0; rr < 4; rr++) mst[rt][rr] = -INFINITY;
  }

  const int wrow_hi = qt * 128 + wv * 32 + 31;

  STAGE_K(j0, 0);
  __syncthreads();
  int cur = 0;

  for (int jj = j0; jj < jend; jj++){
    if (jj + 1 < jend) STAGE_K(jj + 1, cur ^ 1);
    STAGE_V(jj);
    const bool act = (jj * 64 <= wrow_hi);

    f32x4 sv[2][4];
    if (act){
      const char* KsC = (const char*)&Kb[cur][0];
      #pragma unroll
      for (int rt = 0; rt < 2; rt++)
        #pragma unroll
        for (int ct = 0; ct < 4; ct++) sv[rt][ct] = Z;
      #pragma unroll
      for (int ks = 0; ks < 4; ks++){
        const int kb = ks * 64 + rq * 16;
        #pragma unroll
        for (int ct = 0; ct < 4; ct++){
          int r = ct * 16 + cl;
          bf16x8 bfr = *(const bf16x8*)(KsC + r * 256 + (kb ^ ((r & 7) << 4)));
          #pragma unroll
          for (int rt = 0; rt < 2; rt++)
            sv[rt][ct] = __builtin_amdgcn_mfma_f32_16x16x32_bf16(qf[rt][ks], bfr, sv[rt][ct], 0, 0, 0);
        }
      }
    }

    __syncthreads();   // all QK reads of Kb[cur] done; V (and next K) landed

    if (act){
      char* pbase = (char*)&Kb[cur][0] + wv * 4096;   // P overlays consumed K buffer
      const bool msk = (jj >= 2 * qt);

      #pragma unroll
      for (int rt = 0; rt < 2; rt++){
        float p4[4][4], lmx[4];
        #pragma unroll
        for (int rr = 0; rr < 4; rr++) lmx[rr] = -1e30f;
        const int qg = qt * 128 + wv * 32 + rt * 16 + rq * 4;
        #pragma unroll
        for (int ct = 0; ct < 4; ct++){
          int col = jj * 64 + ct * 16 + cl;
          #pragma unroll
          for (int rr = 0; rr < 4; rr++){
            float v = sv[rt][ct][rr];                 // already log2-domain
            if (msk && col > qg + rr) v = -1e30f;
            p4[ct][rr] = v;
            lmx[rr] = fmaxf(lmx[rr], v);
          }
        }
        // defer-max gate: cross-lane reduce + rescale only when needed
        float need = -1e30f;
        #pragma unroll
        for (int rr = 0; rr < 4; rr++) need = fmaxf(need, lmx[rr] - mst[rt][rr]);
        if (__any(need > THR2)){
          float mx[4];
          #pragma unroll
          for (int rr = 0; rr < 4; rr++) mx[rr] = lmx[rr];
          #pragma unroll
          for (int off = 1; off < 16; off <<= 1)
            #pragma unroll
            for (int rr = 0; rr < 4; rr++)
              mx[rr] = fmaxf(mx[rr], __shfl_xor(mx[rr], off, 64));
          #pragma unroll
          for (int rr = 0; rr < 4; rr++){
            float mn  = fmaxf(mst[rt][rr], mx[rr]);
            float fsc = exp2_fast(mst[rt][rr] - mn);
            mst[rt][rr] = mn;
            accl[rt][rr] *= fsc;
            #pragma unroll
            for (int n = 0; n < 8; n++) acco[rt][n][rr] *= fsc;
          }
        }
        #pragma unroll
        for (int ct = 0; ct < 4; ct++)
          #pragma unroll
          for (int rr = 0; rr < 4; rr++){
            float e = exp2_fast(p4[ct][rr] - mst[rt][rr]);
            int wr = rt * 16 + rq * 4 + rr;
            *(u16*)(pbase + wr * 128 + (((ct * 16 + cl) * 2) ^ ((wr & 7) << 4))) = f2bf(e);
          }
      }

      // O += P V ; l += P 1  (V^T from LDS; P per-wave slot, in-wave RAW ordering)
      const char* VsC = (const char*)Vs;
      #pragma unroll
      for (int ks = 0; ks < 2; ks++){
        const int kvb = ks * 64 + rq * 16;
        bf16x8 pa[2];
        #pragma unroll
        for (int rt = 0; rt < 2; rt++){
          int wr = rt * 16 + cl;
          pa[rt] = *(const bf16x8*)(pbase + wr * 128 + (kvb ^ ((wr & 7) << 4)));
          accl[rt] = __builtin_amdgcn_mfma_f32_16x16x32_bf16(pa[rt], ones, accl[rt], 0, 0, 0);
        }
        #pragma unroll
        for (int n = 0; n < 8; n++){
          int r = n * 16 + cl;
          bf16x8 bfr = *(const bf16x8*)(VsC + r * 128 + (kvb ^ ((r & 7) << 4)));
          #pragma unroll
          for (int rt = 0; rt < 2; rt++)
            acco[rt][n] = __builtin_amdgcn_mfma_f32_16x16x32_bf16(pa[rt], bfr, acco[rt][n], 0, 0, 0);
        }
      }
    }

    __syncthreads();   // PV reads of Vs and P done before next iter's staging
    cur ^= 1;
  }

  // write partial (unnormalized O, m(log2), l)
  char* pO = part + (size_t)(bh * NTASK + x) * PSTRIDE;
  #pragma unroll
  for (int rt = 0; rt < 2; rt++)
    #pragma unroll
    for (int rr = 0; rr < 4; rr++){
      int prow = wv * 32 + rt * 16 + rq * 4 + rr;
      #pragma unroll
      for (int n = 0; n < 8; n++)
        ((u16*)pO)[prow * 128 + n * 16 + cl] = f2bf(acco[rt][n][rr]);
    }
  if (cl == 0){
    float* pm = (float*)(pO + 32768);
    float* pl = (float*)(pO + 33280);
    #pragma unroll
    for (int rt = 0; rt < 2; rt++)
      #pragma unroll
      for (int rr = 0; rr < 4; rr++){
        int prow = wv * 32 + rt * 16 + rq * 4 + rr;
        pm[prow] = mst[rt][rr];
        pl[prow] = accl[rt][rr];
      }
  }
}

// combine partials -> aout. grid (qt=16, bh=32), block 256: thread = (row, half-of-d)
__global__ __launch_bounds__(256) void attn_combine_k(
    const char* __restrict__ part, u16* __restrict__ aout)
{
  const int qt = blockIdx.x, bh = blockIdx.y;
  const int b = bh >> 4, h = bh & 15;
  const int tid = threadIdx.x;
  const int row = tid >> 1, d0 = (tid & 1) * 64;
  const int nsp = (qt < 5) ? 1 : (qt < 10) ? 2 : (qt < 15) ? 3 : 4;
  const int st  = (qt < 5) ? qt : (qt < 10) ? (5 + 2*(qt-5)) : (qt < 15) ? (15 + 3*(qt-10)) : 30;

  const char* pb[4];
  float w[4];
  float mg = -INFINITY;
  for (int s2 = 0; s2 < nsp; s2++){
    pb[s2] = part + (size_t)(bh * NTASK + st + s2) * PSTRIDE;
    float m = *(const float*)(pb[s2] + 32768 + row * 4);
    w[s2] = m;
    mg = fmaxf(mg, m);
  }
  float lg = 0.f;
  for (int s2 = 0; s2 < nsp; s2++){
    float e = exp2_fast(w[s2] - mg);   // m is log2-domain
    float l = *(const float*)(pb[s2] + 33280 + row * 4);
    w[s2] = e;
    lg += e * l;
  }
  const float inv = 1.0f / lg;

  u16* orow = aout + (size_t)(b * LL + qt * 128 + row) * HIDD + h * HDD + d0;
  for (int c = 0; c < 8; c++){
    float a[8];
    #pragma unroll
    for (int e = 0; e < 8; e++) a[e] = 0.f;
    for (int s2 = 0; s2 < nsp; s2++){
      bf16x8 v = *(const bf16x8*)((const u16*)pb[s2] + row * 128 + d0 + c * 8);
      #pragma unroll
      for (int e = 0; e < 8; e++) a[e] += w[s2] * (float)v[e];
    }
    ushort4 o0, o1;
    o0.x = f2bf(a[0]*inv); o0.y = f2bf(a[1]*inv); o0.z = f2bf(a[2]*inv); o0.w = f2bf(a[3]*inv);
    o1.x = f2bf(a[4]*inv); o1.y = f2bf(a[5]*inv); o1.z = f2bf(a[6]*inv); o1.w = f2bf(a[7]*inv);
    *(ushort4*)(orow + c * 8)     = o0;
    *(ushort4*)(orow + c * 8 + 4) = o1;
  }
}

// ---------------- launcher ----------------

extern "C" void kernel_launch(void* const* d_in, const int* in_sizes, int n_in,
                              void* d_out, int out_size, void* d_ws, size_t ws_size,
                              hipStream_t stream)
{
  const float* x  = (const float*)d_in[0];
  // d_in[1] = mask (causal; applied analytically)
  const float* Wq = (const float*)d_in[2];
  const float* Wk = (const float*)d_in[3];
  const float* Wv = (const float*)d_in[4];
  const float* Wo = (const float*)d_in[5];
  float* out = (float*)d_out;

  if (ws_size < 134217728ull) return;  // need 128 MB of scratch

  char* ws = (char*)d_ws;
  u16* xb   = (u16*)(ws);                  // 4096x2048 bf16  (16 MB)   dead after gemm1
  u16* Wt   = (u16*)(ws + 16777216ull);    // 6144x2048 bf16  (24 MB)   dead after gemm1
  u16* Wot  = (u16*)(ws + 41943040ull);    // 2048x2048 bf16  ( 8 MB)
  u16* qkv  = (u16*)(ws + 50331648ull);    // 4096x6144 bf16  (48 MB)
  u16* vt   = (u16*)(ws + 100663296ull);   // 32x128x2048 bf16(16 MB)
  u16* aout = (u16*)(ws + 117440512ull);   // 4096x2048 bf16  (16 MB)
  char* part = ws;                          // 1088 x 33KB = 36.8 MB, reuses xb+Wt region

  cvt_f32_bf16_k<<<2097152 / 256, 256, 0, stream>>>(x, xb, 2097152);
  dim3 tb(32, 8);
  transpose_cvt_k<<<dim3(64, 64), tb, 0, stream>>>(Wq, Wt,                   2048, 2048);
  transpose_cvt_k<<<dim3(64, 64), tb, 0, stream>>>(Wk, Wt + 2048 * 2048,     2048, 2048);
  transpose_cvt_k<<<dim3(64, 64), tb, 0, stream>>>(Wv, Wt + 2 * 2048 * 2048, 2048, 2048);
  transpose_cvt_k<<<dim3(64, 64), tb, 0, stream>>>(Wo, Wot,                  2048, 2048);

  gemm_bt_k<1><<<dim3(6144 / 128, 4096 / 128), 256, 0, stream>>>(xb, Wt, qkv, 4096, 6144, 2048);
  rope_k<<<4194304 / 256, 256, 0, stream>>>(qkv);
  build_vt_k<<<dim3(4, 64, 32), tb, 0, stream>>>(qkv, vt);

  attn_split_k<<<dim3(NTASK, 32), 256, 0, stream>>>(qkv, vt, part);
  attn_combine_k<<<dim3(16, 32), 256, 0, stream>>>(part, aout);

  gemm_bt_k<0><<<dim3(2048 / 128, 4096 / 128), 256, 0, stream>>>(aout, Wot, out, 4096, 2048, 2048);
}

// Round 6
// 522.245 us; speedup vs baseline: 1.0552x; 1.0552x over previous
//
#include <hip/hip_runtime.h>
#include <math.h>

#define BB   2
#define LL   2048
#define HIDD 2048
#define NHH  16
#define HDD  128
#define QKVN 6144   // 3*HIDD
#define NTASK 34    // KV-split tasks per (b,h)
#define PSTRIDE 33792  // 32KB partial O + 512B m + 512B l
#define THR2 11.5416f  // defer-max threshold, log2 domain (= 8 nats)

typedef unsigned short u16;
typedef float  f32x4 __attribute__((ext_vector_type(4)));
typedef __bf16 bf16x8 __attribute__((ext_vector_type(8)));

static __device__ __forceinline__ float exp2_fast(float x){
  return __builtin_amdgcn_exp2f(x);    // v_exp_f32 (native 2^x)
}
static __device__ __forceinline__ u16 f2bf(float x){
  unsigned u = __float_as_uint(x);
  return (u16)((u + 0x7fffu + ((u >> 16) & 1u)) >> 16);
}
static __device__ __forceinline__ float bf2f(u16 b){
  return __uint_as_float(((unsigned)b) << 16);
}
static __device__ __forceinline__ void gl_lds16(const void* g, void* l){
  __builtin_amdgcn_global_load_lds(
      (__attribute__((address_space(1))) void*)(void*)g,
      (__attribute__((address_space(3))) void*)l,
      16, 0, 0);
}

// ---------------- prep kernels ----------------

__global__ void cvt_f32_bf16_k(const float* __restrict__ src, u16* __restrict__ dst, int n4){
  int i = blockIdx.x * blockDim.x + threadIdx.x;
  if (i >= n4) return;
  float4 v = ((const float4*)src)[i];
  ushort4 o;
  o.x = f2bf(v.x); o.y = f2bf(v.y); o.z = f2bf(v.z); o.w = f2bf(v.w);
  ((ushort4*)dst)[i] = o;
}

// src: R x C f32 (row-major) -> dst: C x R bf16
__global__ void transpose_cvt_k(const float* __restrict__ src, u16* __restrict__ dst, int R, int C){
  __shared__ float t[32][33];
  int c0 = blockIdx.x * 32, r0 = blockIdx.y * 32;
  int tx = threadIdx.x, ty = threadIdx.y;
  #pragma unroll
  for (int i = 0; i < 32; i += 8) t[ty + i][tx] = src[(size_t)(r0 + ty + i) * C + c0 + tx];
  __syncthreads();
  #pragma unroll
  for (int i = 0; i < 32; i += 8) dst[(size_t)(c0 + ty + i) * R + r0 + tx] = f2bf(t[tx][ty + i]);
}

// in-place RoPE on q,k sections of qkv (bf16). idx over B*L*NH*64
// Q additionally pre-scaled by 1/sqrt(128)*log2(e) so attention scores are
// directly in exp2 domain.
__global__ void rope_k(u16* __restrict__ qkv){
  int idx = blockIdx.x * blockDim.x + threadIdx.x;
  int d   = idx & 63;
  int h   = (idx >> 6) & 15;
  int row = idx >> 10;           // b*L + l
  int l   = row & (LL - 1);
  float fr = __expf(-(float)d * 0.17988946f);   // ln(1e5)/64
  float th = (float)l * 0.25f * fr;             // pos/ROPE_SCALE * freq
  float s, c;
  sincosf(th, &s, &c);
  size_t base = (size_t)row * QKVN + h * HDD + d;
  #pragma unroll
  for (int part = 0; part < 2; part++){         // q then k
    float f = (part == 0) ? 0.12753375f : 1.0f; // scale*log2e folded into Q
    float x1 = bf2f(qkv[base]), x2 = bf2f(qkv[base + 64]);
    qkv[base]      = f2bf((x1 * c - x2 * s) * f);
    qkv[base + 64] = f2bf((x1 * s + x2 * c) * f);
    base += HIDD;
  }
}

// v section of qkv -> vt[(b,h), d, l]
__global__ void build_vt_k(const u16* __restrict__ qkv, u16* __restrict__ vt){
  __shared__ u16 t[32][33];
  int bh = blockIdx.z;
  int b = bh >> 4, h = bh & 15;
  const u16* src = qkv + (size_t)b * LL * QKVN + 2 * HIDD + h * HDD; // [l][d] stride QKVN
  u16* dst = vt + (size_t)bh * HDD * LL;                              // [d][l] stride LL
  int d0 = blockIdx.x * 32, l0 = blockIdx.y * 32;
  int tx = threadIdx.x, ty = threadIdx.y;
  #pragma unroll
  for (int i = 0; i < 32; i += 8) t[ty + i][tx] = src[(size_t)(l0 + ty + i) * QKVN + d0 + tx];
  __syncthreads();
  #pragma unroll
  for (int i = 0; i < 32; i += 8) dst[(size_t)(d0 + ty + i) * LL + l0 + tx] = t[tx][ty + i];
}

// ---------------- GEMM: C[M,N] = A[M,K] * Bt[N,K]^T  (bf16 in, f32 acc) ----------------

template<int OUT_BF16>
__global__ __launch_bounds__(256) void gemm_bt_k(
    const u16* __restrict__ A, const u16* __restrict__ Bt,
    void* __restrict__ Cout, int M, int N, int K)
{
  __shared__ __align__(16) u16 As[128 * 64];
  __shared__ __align__(16) u16 Bs[128 * 64];
  const int tid = threadIdx.x, lane = tid & 63, wv = tid >> 6;
  const int wr = wv >> 1, wc = wv & 1;
  const int m0 = blockIdx.y * 128, n0 = blockIdx.x * 128;
  const int rq = lane >> 4, cl = lane & 15;

  const f32x4 Z = {0.f, 0.f, 0.f, 0.f};
  f32x4 acc[4][4];
  #pragma unroll
  for (int m = 0; m < 4; m++)
    #pragma unroll
    for (int n = 0; n < 4; n++) acc[m][n] = Z;

  for (int kt = 0; kt < K; kt += 64){
    #pragma unroll
    for (int i = 0; i < 4; i++){
      int fb = (i * 4 + wv) * 64;          // wave-uniform 16B-chunk base
      int p  = (fb + lane) * 16;           // this lane's physical LDS byte
      int r  = p >> 7;                     // tile row (128B rows)
      int cbs = (p & 127) ^ ((r & 7) << 4);
      gl_lds16(A  + (size_t)(m0 + r) * K + kt + (cbs >> 1), &As[fb * 8]);
      gl_lds16(Bt + (size_t)(n0 + r) * K + kt + (cbs >> 1), &Bs[fb * 8]);
    }
    __syncthreads();
    #pragma unroll
    for (int ks = 0; ks < 2; ks++){
      const int kb = ks * 64 + rq * 16;    // k byte offset in row
      bf16x8 a[4], b[4];
      #pragma unroll
      for (int m = 0; m < 4; m++){
        int r = wr * 64 + m * 16 + cl;
        a[m] = *(const bf16x8*)((const char*)As + r * 128 + (kb ^ ((r & 7) << 4)));
      }
      #pragma unroll
      for (int n = 0; n < 4; n++){
        int r = wc * 64 + n * 16 + cl;
        b[n] = *(const bf16x8*)((const char*)Bs + r * 128 + (kb ^ ((r & 7) << 4)));
      }
      #pragma unroll
      for (int m = 0; m < 4; m++)
        #pragma unroll
        for (int n = 0; n < 4; n++)
          acc[m][n] = __builtin_amdgcn_mfma_f32_16x16x32_bf16(a[m], b[n], acc[m][n], 0, 0, 0);
    }
    __syncthreads();
  }

  #pragma unroll
  for (int m = 0; m < 4; m++){
    int gr0 = m0 + wr * 64 + m * 16 + rq * 4;
    #pragma unroll
    for (int n = 0; n < 4; n++){
      int gc = n0 + wc * 64 + n * 16 + cl;
      #pragma unroll
      for (int rr = 0; rr < 4; rr++){
        if (OUT_BF16) ((u16*)Cout)[(size_t)(gr0 + rr) * N + gc] = f2bf(acc[m][n][rr]);
        else          ((float*)Cout)[(size_t)(gr0 + rr) * N + gc] = acc[m][n][rr];
      }
    }
  }
}

// ---------------- flash attention, KV-split, staged K/V, lean softmax ----------------
// grid (bh=32 fast, task): XCD = bh%8 -> per-XCD L2 holds its 4 bh-sets' K/V.
// Task x: balanced KV-chunk of q-tile qt (128 rows). 4 waves x 32 q-rows.
// K double-buffered in LDS; V single-buffered; P reuses the consumed K buffer.
// Row-sum via ones-column MFMA; defer-max gate; coalesced partial write via LDS.

#define STAGE_K(jj, bsel) do {                                                            \
  const int kv0_ = (jj) * 64;                                                             \
  _Pragma("unroll")                                                                       \
  for (int i_ = 0; i_ < 4; i_++){                                                         \
    int fb_ = (i_ * 4 + wv) * 64;                                                         \
    int p_  = (fb_ + lane) * 16;                                                          \
    int r_ = p_ >> 8; int cb_ = (p_ & 255) ^ ((r_ & 7) << 4);                             \
    gl_lds16(qkv + (size_t)(b * LL + kv0_ + r_) * QKVN + HIDD + h * HDD + (cb_ >> 1),     \
             &Kb[bsel][fb_ * 8]);                                                         \
  }                                                                                       \
} while(0)

#define STAGE_V(jj) do {                                                                  \
  const int kv0_ = (jj) * 64;                                                             \
  _Pragma("unroll")                                                                       \
  for (int i_ = 0; i_ < 4; i_++){                                                         \
    int fb_ = (i_ * 4 + wv) * 64;                                                         \
    int p_  = (fb_ + lane) * 16;                                                          \
    int r_ = p_ >> 7; int cb_ = (p_ & 127) ^ ((r_ & 7) << 4);                             \
    gl_lds16(vt + (size_t)(bh * HDD + r_) * LL + kv0_ + (cb_ >> 1), &Vs[fb_ * 8]);        \
  }                                                                                       \
} while(0)

__global__ __launch_bounds__(256, 3) void attn_split_k(
    const u16* __restrict__ qkv, const u16* __restrict__ vt,
    char* __restrict__ part)
{
  __shared__ __align__(16) u16 Kb[2][64 * 128];   // K tiles [64][128], 2x16KB
  __shared__ __align__(16) u16 Vs[128 * 64];      // V^T tile [128][64], 16KB
  const int tid = threadIdx.x, lane = tid & 63, wv = tid >> 6;
  const int bh = blockIdx.x;                      // fast dim -> XCD = bh % 8
  const int x  = (NTASK - 1) - (int)blockIdx.y;   // big tasks dispatch first
  const int b = bh >> 4, h = bh & 15;
  const int rq = lane >> 4, cl = lane & 15;

  int qt, s, nsp;
  if      (x <  5) { qt = x;                 s = 0;           nsp = 1; }
  else if (x < 15) { qt = 5 + ((x-5) >> 1);  s = (x-5) & 1;   nsp = 2; }
  else if (x < 30) { qt = 10 + (x-15)/3;     s = (x-15)%3;    nsp = 3; }
  else             { qt = 15;                s = x - 30;      nsp = 4; }
  const int T    = 2 * (qt + 1);
  const int base = T / nsp, rem = T % nsp;
  const int j0   = s * base + (s < rem ? s : rem);
  const int jend = j0 + base + (s < rem ? 1 : 0);

  // Q fragments (already scaled by 1/sqrt(d)*log2e in rope_k)
  bf16x8 qf[2][4];
  #pragma unroll
  for (int rt = 0; rt < 2; rt++){
    const u16* qb = qkv + (size_t)(b * LL + qt * 128 + wv * 32 + rt * 16 + cl) * QKVN + h * HDD + rq * 8;
    #pragma unroll
    for (int ks = 0; ks < 4; ks++) qf[rt][ks] = *(const bf16x8*)(qb + ks * 32);
  }

  bf16x8 ones;
  #pragma unroll
  for (int i = 0; i < 8; i++) ones[i] = (__bf16)1.0f;

  const f32x4 Z = {0.f, 0.f, 0.f, 0.f};
  f32x4 acco[2][8];
  f32x4 accl[2];                 // row-sum accumulator (ones-column MFMA)
  float mst[2][4];
  #pragma unroll
  for (int rt = 0; rt < 2; rt++){
    #pragma unroll
    for (int n = 0; n < 8; n++) acco[rt][n] = Z;
    accl[rt] = Z;
    #pragma unroll
    for (int rr = 0; rr < 4; rr++) mst[rt][rr] = -INFINITY;
  }

  const int wrow_hi = qt * 128 + wv * 32 + 31;

  STAGE_K(j0, 0);
  __syncthreads();
  int cur = 0;

  for (int jj = j0; jj < jend; jj++){
    if (jj + 1 < jend) STAGE_K(jj + 1, cur ^ 1);
    STAGE_V(jj);
    const bool act = (jj * 64 <= wrow_hi);

    f32x4 sv[2][4];
    if (act){
      const char* KsC = (const char*)&Kb[cur][0];
      #pragma unroll
      for (int rt = 0; rt < 2; rt++)
        #pragma unroll
        for (int ct = 0; ct < 4; ct++) sv[rt][ct] = Z;
      #pragma unroll
      for (int ks = 0; ks < 4; ks++){
        const int kb = ks * 64 + rq * 16;
        #pragma unroll
        for (int ct = 0; ct < 4; ct++){
          int r = ct * 16 + cl;
          bf16x8 bfr = *(const bf16x8*)(KsC + r * 256 + (kb ^ ((r & 7) << 4)));
          #pragma unroll
          for (int rt = 0; rt < 2; rt++)
            sv[rt][ct] = __builtin_amdgcn_mfma_f32_16x16x32_bf16(qf[rt][ks], bfr, sv[rt][ct], 0, 0, 0);
        }
      }
    }

    __syncthreads();   // all QK reads of Kb[cur] done; V (and next K) landed

    if (act){
      char* pbase = (char*)&Kb[cur][0] + wv * 4096;   // P overlays consumed K buffer
      const bool msk = (jj >= 2 * qt);

      #pragma unroll
      for (int rt = 0; rt < 2; rt++){
        float p4[4][4], lmx[4];
        #pragma unroll
        for (int rr = 0; rr < 4; rr++) lmx[rr] = -1e30f;
        const int qg = qt * 128 + wv * 32 + rt * 16 + rq * 4;
        #pragma unroll
        for (int ct = 0; ct < 4; ct++){
          int col = jj * 64 + ct * 16 + cl;
          #pragma unroll
          for (int rr = 0; rr < 4; rr++){
            float v = sv[rt][ct][rr];                 // already log2-domain
            if (msk && col > qg + rr) v = -1e30f;
            p4[ct][rr] = v;
            lmx[rr] = fmaxf(lmx[rr], v);
          }
        }
        // defer-max gate: cross-lane reduce + rescale only when needed
        float need = -1e30f;
        #pragma unroll
        for (int rr = 0; rr < 4; rr++) need = fmaxf(need, lmx[rr] - mst[rt][rr]);
        if (__any(need > THR2)){
          float mx[4];
          #pragma unroll
          for (int rr = 0; rr < 4; rr++) mx[rr] = lmx[rr];
          #pragma unroll
          for (int off = 1; off < 16; off <<= 1)
            #pragma unroll
            for (int rr = 0; rr < 4; rr++)
              mx[rr] = fmaxf(mx[rr], __shfl_xor(mx[rr], off, 64));
          #pragma unroll
          for (int rr = 0; rr < 4; rr++){
            float mn  = fmaxf(mst[rt][rr], mx[rr]);
            float fsc = exp2_fast(mst[rt][rr] - mn);
            mst[rt][rr] = mn;
            accl[rt][rr] *= fsc;
            #pragma unroll
            for (int n = 0; n < 8; n++) acco[rt][n][rr] *= fsc;
          }
        }
        #pragma unroll
        for (int ct = 0; ct < 4; ct++)
          #pragma unroll
          for (int rr = 0; rr < 4; rr++){
            float e = exp2_fast(p4[ct][rr] - mst[rt][rr]);
            int wr = rt * 16 + rq * 4 + rr;
            *(u16*)(pbase + wr * 128 + (((ct * 16 + cl) * 2) ^ ((wr & 7) << 4))) = f2bf(e);
          }
      }

      // O += P V ; l += P 1  (V^T from LDS; P per-wave slot, in-wave RAW ordering)
      const char* VsC = (const char*)Vs;
      #pragma unroll
      for (int ks = 0; ks < 2; ks++){
        const int kvb = ks * 64 + rq * 16;
        bf16x8 pa[2];
        #pragma unroll
        for (int rt = 0; rt < 2; rt++){
          int wr = rt * 16 + cl;
          pa[rt] = *(const bf16x8*)(pbase + wr * 128 + (kvb ^ ((wr & 7) << 4)));
          accl[rt] = __builtin_amdgcn_mfma_f32_16x16x32_bf16(pa[rt], ones, accl[rt], 0, 0, 0);
        }
        #pragma unroll
        for (int n = 0; n < 8; n++){
          int r = n * 16 + cl;
          bf16x8 bfr = *(const bf16x8*)(VsC + r * 128 + (kvb ^ ((r & 7) << 4)));
          #pragma unroll
          for (int rt = 0; rt < 2; rt++)
            acco[rt][n] = __builtin_amdgcn_mfma_f32_16x16x32_bf16(pa[rt], bfr, acco[rt][n], 0, 0, 0);
        }
      }
    }

    __syncthreads();   // PV reads of Vs and P done before next iter's staging
    cur ^= 1;
  }

  // ---- coalesced partial write: C-layout -> row-major via per-wave LDS slice ----
  __syncthreads();                       // all PV done; Kb free as scratch
  u16* tb = &Kb[0][0] + wv * 4096;       // 8KB per wave (Kb[0]+Kb[1] = 32KB total)
  #pragma unroll
  for (int rt = 0; rt < 2; rt++)
    #pragma unroll
    for (int n = 0; n < 8; n++)
      #pragma unroll
      for (int rr = 0; rr < 4; rr++)
        tb[(rt * 16 + rq * 4 + rr) * 128 + n * 16 + cl] = f2bf(acco[rt][n][rr]);

  u16* pO16 = (u16*)(part + (size_t)(bh * NTASK + x) * PSTRIDE);
  #pragma unroll
  for (int p = 0; p < 8; p++){
    int r = p * 4 + rq;
    bf16x8 v = *(const bf16x8*)(tb + r * 128 + cl * 8);
    *(bf16x8*)(pO16 + (wv * 32 + r) * 128 + cl * 8) = v;   // 16B coalesced store
  }
  if (cl == 0){
    float* pm = (float*)((char*)pO16 + 32768);
    float* pl = (float*)((char*)pO16 + 33280);
    #pragma unroll
    for (int rt = 0; rt < 2; rt++)
      #pragma unroll
      for (int rr = 0; rr < 4; rr++){
        int prow = wv * 32 + rt * 16 + rq * 4 + rr;
        pm[prow] = mst[rt][rr];
        pl[prow] = accl[rt][rr];
      }
  }
}

// combine partials -> aout. grid (qt=16, bh=32), block 256: thread = (row, half-of-d)
__global__ __launch_bounds__(256) void attn_combine_k(
    const char* __restrict__ part, u16* __restrict__ aout)
{
  const int qt = blockIdx.x, bh = blockIdx.y;
  const int b = bh >> 4, h = bh & 15;
  const int tid = threadIdx.x;
  const int row = tid >> 1, d0 = (tid & 1) * 64;
  const int nsp = (qt < 5) ? 1 : (qt < 10) ? 2 : (qt < 15) ? 3 : 4;
  const int st  = (qt < 5) ? qt : (qt < 10) ? (5 + 2*(qt-5)) : (qt < 15) ? (15 + 3*(qt-10)) : 30;

  const char* pb[4];
  float w[4];
  float mg = -INFINITY;
  for (int s2 = 0; s2 < nsp; s2++){
    pb[s2] = part + (size_t)(bh * NTASK + st + s2) * PSTRIDE;
    float m = *(const float*)(pb[s2] + 32768 + row * 4);
    w[s2] = m;
    mg = fmaxf(mg, m);
  }
  float lg = 0.f;
  for (int s2 = 0; s2 < nsp; s2++){
    float e = exp2_fast(w[s2] - mg);   // m is log2-domain
    float l = *(const float*)(pb[s2] + 33280 + row * 4);
    w[s2] = e;
    lg += e * l;
  }
  const float inv = 1.0f / lg;

  u16* orow = aout + (size_t)(b * LL + qt * 128 + row) * HIDD + h * HDD + d0;
  for (int c = 0; c < 8; c++){
    float a[8];
    #pragma unroll
    for (int e = 0; e < 8; e++) a[e] = 0.f;
    for (int s2 = 0; s2 < nsp; s2++){
      bf16x8 v = *(const bf16x8*)((const u16*)pb[s2] + row * 128 + d0 + c * 8);
      #pragma unroll
      for (int e = 0; e < 8; e++) a[e] += w[s2] * (float)v[e];
    }
    ushort4 o0, o1;
    o0.x = f2bf(a[0]*inv); o0.y = f2bf(a[1]*inv); o0.z = f2bf(a[2]*inv); o0.w = f2bf(a[3]*inv);
    o1.x = f2bf(a[4]*inv); o1.y = f2bf(a[5]*inv); o1.z = f2bf(a[6]*inv); o1.w = f2bf(a[7]*inv);
    *(ushort4*)(orow + c * 8)     = o0;
    *(ushort4*)(orow + c * 8 + 4) = o1;
  }
}

// ---------------- launcher ----------------

extern "C" void kernel_launch(void* const* d_in, const int* in_sizes, int n_in,
                              void* d_out, int out_size, void* d_ws, size_t ws_size,
                              hipStream_t stream)
{
  const float* x  = (const float*)d_in[0];
  // d_in[1] = mask (causal; applied analytically)
  const float* Wq = (const float*)d_in[2];
  const float* Wk = (const float*)d_in[3];
  const float* Wv = (const float*)d_in[4];
  const float* Wo = (const float*)d_in[5];
  float* out = (float*)d_out;

  if (ws_size < 134217728ull) return;  // need 128 MB of scratch

  char* ws = (char*)d_ws;
  u16* xb   = (u16*)(ws);                  // 4096x2048 bf16  (16 MB)   dead after gemm1
  u16* Wt   = (u16*)(ws + 16777216ull);    // 6144x2048 bf16  (24 MB)   dead after gemm1
  u16* Wot  = (u16*)(ws + 41943040ull);    // 2048x2048 bf16  ( 8 MB)
  u16* qkv  = (u16*)(ws + 50331648ull);    // 4096x6144 bf16  (48 MB)
  u16* vt   = (u16*)(ws + 100663296ull);   // 32x128x2048 bf16(16 MB)
  u16* aout = (u16*)(ws + 117440512ull);   // 4096x2048 bf16  (16 MB)
  char* part = ws;                          // 1088 x 33KB = 36.8 MB, reuses xb+Wt region

  cvt_f32_bf16_k<<<2097152 / 256, 256, 0, stream>>>(x, xb, 2097152);
  dim3 tb(32, 8);
  transpose_cvt_k<<<dim3(64, 64), tb, 0, stream>>>(Wq, Wt,                   2048, 2048);
  transpose_cvt_k<<<dim3(64, 64), tb, 0, stream>>>(Wk, Wt + 2048 * 2048,     2048, 2048);
  transpose_cvt_k<<<dim3(64, 64), tb, 0, stream>>>(Wv, Wt + 2 * 2048 * 2048, 2048, 2048);
  transpose_cvt_k<<<dim3(64, 64), tb, 0, stream>>>(Wo, Wot,                  2048, 2048);

  gemm_bt_k<1><<<dim3(6144 / 128, 4096 / 128), 256, 0, stream>>>(xb, Wt, qkv, 4096, 6144, 2048);
  rope_k<<<4194304 / 256, 256, 0, stream>>>(qkv);
  build_vt_k<<<dim3(4, 64, 32), tb, 0, stream>>>(qkv, vt);

  attn_split_k<<<dim3(32, NTASK), 256, 0, stream>>>(qkv, vt, part);
  attn_combine_k<<<dim3(16, 32), 256, 0, stream>>>(part, aout);

  gemm_bt_k<0><<<dim3(2048 / 128, 4096 / 128), 256, 0, stream>>>(aout, Wot, out, 4096, 2048, 2048);
}

// Round 7
// 290.396 us; speedup vs baseline: 1.8977x; 1.7984x over previous
//
#include <hip/hip_runtime.h>
#include <math.h>

#define BB   2
#define LL   2048
#define HIDD 2048
#define NHH  16
#define HDD  128
#define QKVN 6144   // 3*HIDD
#define THR2 11.5416f  // defer-max threshold, log2 domain (= 8 nats)

typedef unsigned short u16;
typedef float  f32x4 __attribute__((ext_vector_type(4)));
typedef __bf16 bf16x8 __attribute__((ext_vector_type(8)));

static __device__ __forceinline__ float exp2_fast(float x){
  return __builtin_amdgcn_exp2f(x);    // v_exp_f32 (native 2^x)
}
static __device__ __forceinline__ u16 f2bf(float x){
  unsigned u = __float_as_uint(x);
  return (u16)((u + 0x7fffu + ((u >> 16) & 1u)) >> 16);
}
static __device__ __forceinline__ float bf2f(u16 b){
  return __uint_as_float(((unsigned)b) << 16);
}
static __device__ __forceinline__ void gl_lds16(const void* g, void* l){
  __builtin_amdgcn_global_load_lds(
      (__attribute__((address_space(1))) void*)(void*)g,
      (__attribute__((address_space(3))) void*)l,
      16, 0, 0);
}

// ---------------- prep kernels ----------------

__global__ void cvt_f32_bf16_k(const float* __restrict__ src, u16* __restrict__ dst, int n4){
  int i = blockIdx.x * blockDim.x + threadIdx.x;
  if (i >= n4) return;
  float4 v = ((const float4*)src)[i];
  ushort4 o;
  o.x = f2bf(v.x); o.y = f2bf(v.y); o.z = f2bf(v.z); o.w = f2bf(v.w);
  ((ushort4*)dst)[i] = o;
}

// src: R x C f32 (row-major) -> dst: C x R bf16
__global__ void transpose_cvt_k(const float* __restrict__ src, u16* __restrict__ dst, int R, int C){
  __shared__ float t[32][33];
  int c0 = blockIdx.x * 32, r0 = blockIdx.y * 32;
  int tx = threadIdx.x, ty = threadIdx.y;
  #pragma unroll
  for (int i = 0; i < 32; i += 8) t[ty + i][tx] = src[(size_t)(r0 + ty + i) * C + c0 + tx];
  __syncthreads();
  #pragma unroll
  for (int i = 0; i < 32; i += 8) dst[(size_t)(c0 + ty + i) * R + r0 + tx] = f2bf(t[tx][ty + i]);
}

// in-place RoPE on q,k sections of qkv (bf16). idx over B*L*NH*64
// Q additionally pre-scaled by 1/sqrt(128)*log2(e) -> scores in exp2 domain.
__global__ void rope_k(u16* __restrict__ qkv){
  int idx = blockIdx.x * blockDim.x + threadIdx.x;
  int d   = idx & 63;
  int h   = (idx >> 6) & 15;
  int row = idx >> 10;           // b*L + l
  int l   = row & (LL - 1);
  float fr = __expf(-(float)d * 0.17988946f);   // ln(1e5)/64
  float th = (float)l * 0.25f * fr;             // pos/ROPE_SCALE * freq
  float s, c;
  sincosf(th, &s, &c);
  size_t base = (size_t)row * QKVN + h * HDD + d;
  #pragma unroll
  for (int part = 0; part < 2; part++){         // q then k
    float f = (part == 0) ? 0.12753375f : 1.0f; // scale*log2e folded into Q
    float x1 = bf2f(qkv[base]), x2 = bf2f(qkv[base + 64]);
    qkv[base]      = f2bf((x1 * c - x2 * s) * f);
    qkv[base + 64] = f2bf((x1 * s + x2 * c) * f);
    base += HIDD;
  }
}

// v section of qkv -> vt[(b,h), d, l]
__global__ void build_vt_k(const u16* __restrict__ qkv, u16* __restrict__ vt){
  __shared__ u16 t[32][33];
  int bh = blockIdx.z;
  int b = bh >> 4, h = bh & 15;
  const u16* src = qkv + (size_t)b * LL * QKVN + 2 * HIDD + h * HDD; // [l][d] stride QKVN
  u16* dst = vt + (size_t)bh * HDD * LL;                              // [d][l] stride LL
  int d0 = blockIdx.x * 32, l0 = blockIdx.y * 32;
  int tx = threadIdx.x, ty = threadIdx.y;
  #pragma unroll
  for (int i = 0; i < 32; i += 8) t[ty + i][tx] = src[(size_t)(l0 + ty + i) * QKVN + d0 + tx];
  __syncthreads();
  #pragma unroll
  for (int i = 0; i < 32; i += 8) dst[(size_t)(d0 + ty + i) * LL + l0 + tx] = t[tx][ty + i];
}

// ---------------- GEMM: C[M,N] = A[M,K] * Bt[N,K]^T  (bf16 in, f32 acc) ----------------

template<int OUT_BF16>
__global__ __launch_bounds__(256) void gemm_bt_k(
    const u16* __restrict__ A, const u16* __restrict__ Bt,
    void* __restrict__ Cout, int M, int N, int K)
{
  __shared__ __align__(16) u16 As[128 * 64];
  __shared__ __align__(16) u16 Bs[128 * 64];
  const int tid = threadIdx.x, lane = tid & 63, wv = tid >> 6;
  const int wr = wv >> 1, wc = wv & 1;
  const int m0 = blockIdx.y * 128, n0 = blockIdx.x * 128;
  const int rq = lane >> 4, cl = lane & 15;

  const f32x4 Z = {0.f, 0.f, 0.f, 0.f};
  f32x4 acc[4][4];
  #pragma unroll
  for (int m = 0; m < 4; m++)
    #pragma unroll
    for (int n = 0; n < 4; n++) acc[m][n] = Z;

  for (int kt = 0; kt < K; kt += 64){
    #pragma unroll
    for (int i = 0; i < 4; i++){
      int fb = (i * 4 + wv) * 64;          // wave-uniform 16B-chunk base
      int p  = (fb + lane) * 16;           // this lane's physical LDS byte
      int r  = p >> 7;                     // tile row (128B rows)
      int cbs = (p & 127) ^ ((r & 7) << 4);
      gl_lds16(A  + (size_t)(m0 + r) * K + kt + (cbs >> 1), &As[fb * 8]);
      gl_lds16(Bt + (size_t)(n0 + r) * K + kt + (cbs >> 1), &Bs[fb * 8]);
    }
    __syncthreads();
    #pragma unroll
    for (int ks = 0; ks < 2; ks++){
      const int kb = ks * 64 + rq * 16;    // k byte offset in row
      bf16x8 a[4], b[4];
      #pragma unroll
      for (int m = 0; m < 4; m++){
        int r = wr * 64 + m * 16 + cl;
        a[m] = *(const bf16x8*)((const char*)As + r * 128 + (kb ^ ((r & 7) << 4)));
      }
      #pragma unroll
      for (int n = 0; n < 4; n++){
        int r = wc * 64 + n * 16 + cl;
        b[n] = *(const bf16x8*)((const char*)Bs + r * 128 + (kb ^ ((r & 7) << 4)));
      }
      #pragma unroll
      for (int m = 0; m < 4; m++)
        #pragma unroll
        for (int n = 0; n < 4; n++)
          acc[m][n] = __builtin_amdgcn_mfma_f32_16x16x32_bf16(a[m], b[n], acc[m][n], 0, 0, 0);
    }
    __syncthreads();
  }

  #pragma unroll
  for (int m = 0; m < 4; m++){
    int gr0 = m0 + wr * 64 + m * 16 + rq * 4;
    #pragma unroll
    for (int n = 0; n < 4; n++){
      int gc = n0 + wc * 64 + n * 16 + cl;
      #pragma unroll
      for (int rr = 0; rr < 4; rr++){
        if (OUT_BF16) ((u16*)Cout)[(size_t)(gr0 + rr) * N + gc] = f2bf(acc[m][n][rr]);
        else          ((float*)Cout)[(size_t)(gr0 + rr) * N + gc] = acc[m][n][rr];
      }
    }
  }
}

// ---------------- flash attention: paired q-tiles, uniform blocks ----------------
// grid (bh=32 fast, pair p=0..7), 512 threads = 8 waves x 16 q-rows.
// Block processes q-tile (15-p) [2(15-p)+2 tiles] then q-tile p [2p+2 tiles]:
// exactly 34 tile-iters per block -> perfect balance, lockstep K/V scanning
// in phase A -> L2 single-fetch. K double-buffered (prefetch crosses the phase
// boundary), V single-buffered, P overlays the consumed K buffer.
// Softmax: exp2 domain, ones-MFMA row-sum, gated defer-max. Direct aout write.

#define STAGE_K(jj, bsel) do {                                                            \
  _Pragma("unroll")                                                                       \
  for (int i_ = 0; i_ < 2; i_++){                                                         \
    int fb_ = (i_ * 8 + wv) * 64;                                                         \
    int p_  = (fb_ + lane) * 16;                                                          \
    int r_ = p_ >> 8; int cb_ = (p_ & 255) ^ ((r_ & 7) << 4);                             \
    gl_lds16(qkv + (size_t)(b * LL + (jj) * 64 + r_) * QKVN + HIDD + h * HDD + (cb_ >> 1),\
             &Kb[bsel][fb_ * 8]);                                                         \
  }                                                                                       \
} while(0)

#define STAGE_V(jj) do {                                                                  \
  _Pragma("unroll")                                                                       \
  for (int i_ = 0; i_ < 2; i_++){                                                         \
    int fb_ = (i_ * 8 + wv) * 64;                                                         \
    int p_  = (fb_ + lane) * 16;                                                          \
    int r_ = p_ >> 7; int cb_ = (p_ & 127) ^ ((r_ & 7) << 4);                             \
    gl_lds16(vt + (size_t)(bh * HDD + r_) * LL + (jj) * 64 + (cb_ >> 1), &Vs[fb_ * 8]);   \
  }                                                                                       \
} while(0)

__global__ __launch_bounds__(512, 1) void attn_k(
    const u16* __restrict__ qkv, const u16* __restrict__ vt,
    u16* __restrict__ aout)
{
  __shared__ __align__(16) u16 Kb[2][64 * 128];   // K tiles [64][128], 2x16KB
  __shared__ __align__(16) u16 Vs[128 * 64];      // V^T tile [128][64], 16KB
  const int tid = threadIdx.x, lane = tid & 63, wv = tid >> 6;
  const int bh = blockIdx.x;                      // fast dim -> XCD = bh % 8
  const int pr = blockIdx.y;                      // pair index 0..7
  const int b = bh >> 4, h = bh & 15;
  const int rq = lane >> 4, cl = lane & 15;

  bf16x8 ones;
  #pragma unroll
  for (int i = 0; i < 8; i++) ones[i] = (__bf16)1.0f;
  const f32x4 Z = {0.f, 0.f, 0.f, 0.f};

  int cur = 0;
  STAGE_K(0, 0);                                  // phase-A tile 0

  #pragma unroll
  for (int ph = 0; ph < 2; ph++){
    const int qt = ph ? pr : (15 - pr);
    const int nj = 2 * qt + 2;

    // Q fragments for this q-tile: wave rows qt*128 + wv*16 + cl
    bf16x8 qf[4];
    {
      const u16* qb = qkv + (size_t)(b * LL + qt * 128 + wv * 16 + cl) * QKVN + h * HDD + rq * 8;
      #pragma unroll
      for (int ks = 0; ks < 4; ks++) qf[ks] = *(const bf16x8*)(qb + ks * 32);
    }

    f32x4 acco[8], accl;
    float mst[4];
    #pragma unroll
    for (int n = 0; n < 8; n++) acco[n] = Z;
    accl = Z;
    #pragma unroll
    for (int rr = 0; rr < 4; rr++) mst[rr] = -INFINITY;

    const int wrow_hi = qt * 128 + wv * 16 + 15;

    if (ph == 0) __syncthreads();                 // initial K landed

    for (int j = 0; j < nj; j++){
      // prefetch next K tile (crosses the phase boundary into phase B's j=0)
      if (j + 1 < nj)      STAGE_K(j + 1, cur ^ 1);
      else if (ph == 0)    STAGE_K(0,     cur ^ 1);
      STAGE_V(j);
      const bool act = (j * 64 <= wrow_hi);

      f32x4 sv[4];
      if (act){
        const char* KsC = (const char*)&Kb[cur][0];
        #pragma unroll
        for (int ct = 0; ct < 4; ct++) sv[ct] = Z;
        #pragma unroll
        for (int ks = 0; ks < 4; ks++){
          const int kb = ks * 64 + rq * 16;
          #pragma unroll
          for (int ct = 0; ct < 4; ct++){
            int r = ct * 16 + cl;
            bf16x8 bfr = *(const bf16x8*)(KsC + r * 256 + (kb ^ ((r & 7) << 4)));
            sv[ct] = __builtin_amdgcn_mfma_f32_16x16x32_bf16(qf[ks], bfr, sv[ct], 0, 0, 0);
          }
        }
      }

      __syncthreads();   // QK reads of Kb[cur] done; V (and next K) landed

      if (act){
        char* pbase = (char*)&Kb[cur][0] + wv * 2048;   // P overlays consumed K
        const bool msk = (j >= 2 * qt);

        float p4[4][4], lmx[4];
        #pragma unroll
        for (int rr = 0; rr < 4; rr++) lmx[rr] = -1e30f;
        const int qg = qt * 128 + wv * 16 + rq * 4;
        #pragma unroll
        for (int ct = 0; ct < 4; ct++){
          int col = j * 64 + ct * 16 + cl;
          #pragma unroll
          for (int rr = 0; rr < 4; rr++){
            float v = sv[ct][rr];                 // already log2-domain
            if (msk && col > qg + rr) v = -1e30f;
            p4[ct][rr] = v;
            lmx[rr] = fmaxf(lmx[rr], v);
          }
        }
        // defer-max gate
        float need = -1e30f;
        #pragma unroll
        for (int rr = 0; rr < 4; rr++) need = fmaxf(need, lmx[rr] - mst[rr]);
        if (__any(need > THR2)){
          float mx[4];
          #pragma unroll
          for (int rr = 0; rr < 4; rr++) mx[rr] = lmx[rr];
          #pragma unroll
          for (int off = 1; off < 16; off <<= 1)
            #pragma unroll
            for (int rr = 0; rr < 4; rr++)
              mx[rr] = fmaxf(mx[rr], __shfl_xor(mx[rr], off, 64));
          #pragma unroll
          for (int rr = 0; rr < 4; rr++){
            float mn  = fmaxf(mst[rr], mx[rr]);
            float fsc = exp2_fast(mst[rr] - mn);
            mst[rr] = mn;
            accl[rr] *= fsc;
            #pragma unroll
            for (int n = 0; n < 8; n++) acco[n][rr] *= fsc;
          }
        }
        #pragma unroll
        for (int ct = 0; ct < 4; ct++)
          #pragma unroll
          for (int rr = 0; rr < 4; rr++){
            float e = exp2_fast(p4[ct][rr] - mst[rr]);
            int wr = rq * 4 + rr;
            *(u16*)(pbase + wr * 128 + (((ct * 16 + cl) * 2) ^ ((wr & 7) << 4))) = f2bf(e);
          }

        // O += P V ; l += P 1
        const char* VsC = (const char*)Vs;
        #pragma unroll
        for (int ks = 0; ks < 2; ks++){
          const int kvb = ks * 64 + rq * 16;
          bf16x8 pa = *(const bf16x8*)(pbase + cl * 128 + (kvb ^ ((cl & 7) << 4)));
          accl = __builtin_amdgcn_mfma_f32_16x16x32_bf16(pa, ones, accl, 0, 0, 0);
          #pragma unroll
          for (int n = 0; n < 8; n++){
            int r = n * 16 + cl;
            bf16x8 bfr = *(const bf16x8*)(VsC + r * 128 + (kvb ^ ((r & 7) << 4)));
            acco[n] = __builtin_amdgcn_mfma_f32_16x16x32_bf16(pa, bfr, acco[n], 0, 0, 0);
          }
        }
      }

      __syncthreads();   // Vs + P reads done before next iter's staging
      cur ^= 1;
    }

    // direct write-out (round-2 style; proven unamplified by L2 write-combine)
    #pragma unroll
    for (int rr = 0; rr < 4; rr++){
      float inv = 1.0f / accl[rr];
      size_t grow = (size_t)(b * LL + qt * 128 + wv * 16 + rq * 4 + rr);
      #pragma unroll
      for (int n = 0; n < 8; n++)
        aout[grow * HIDD + h * HDD + n * 16 + cl] = f2bf(acco[n][rr] * inv);
    }
  }
}

// ---------------- launcher ----------------

extern "C" void kernel_launch(void* const* d_in, const int* in_sizes, int n_in,
                              void* d_out, int out_size, void* d_ws, size_t ws_size,
                              hipStream_t stream)
{
  const float* x  = (const float*)d_in[0];
  // d_in[1] = mask (causal; applied analytically)
  const float* Wq = (const float*)d_in[2];
  const float* Wk = (const float*)d_in[3];
  const float* Wv = (const float*)d_in[4];
  const float* Wo = (const float*)d_in[5];
  float* out = (float*)d_out;

  if (ws_size < 134217728ull) return;  // need 128 MB of scratch

  char* ws = (char*)d_ws;
  u16* xb   = (u16*)(ws);                  // 4096x2048 bf16  (16 MB)
  u16* Wt   = (u16*)(ws + 16777216ull);    // 6144x2048 bf16  (24 MB) = [Wq|Wk|Wv]^T
  u16* Wot  = (u16*)(ws + 41943040ull);    // 2048x2048 bf16  ( 8 MB)
  u16* qkv  = (u16*)(ws + 50331648ull);    // 4096x6144 bf16  (48 MB)
  u16* vt   = (u16*)(ws + 100663296ull);   // 32x128x2048 bf16(16 MB)
  u16* aout = (u16*)(ws + 117440512ull);   // 4096x2048 bf16  (16 MB)

  cvt_f32_bf16_k<<<2097152 / 256, 256, 0, stream>>>(x, xb, 2097152);
  dim3 tb(32, 8);
  transpose_cvt_k<<<dim3(64, 64), tb, 0, stream>>>(Wq, Wt,                   2048, 2048);
  transpose_cvt_k<<<dim3(64, 64), tb, 0, stream>>>(Wk, Wt + 2048 * 2048,     2048, 2048);
  transpose_cvt_k<<<dim3(64, 64), tb, 0, stream>>>(Wv, Wt + 2 * 2048 * 2048, 2048, 2048);
  transpose_cvt_k<<<dim3(64, 64), tb, 0, stream>>>(Wo, Wot,                  2048, 2048);

  gemm_bt_k<1><<<dim3(6144 / 128, 4096 / 128), 256, 0, stream>>>(xb, Wt, qkv, 4096, 6144, 2048);
  rope_k<<<4194304 / 256, 256, 0, stream>>>(qkv);
  build_vt_k<<<dim3(4, 64, 32), tb, 0, stream>>>(qkv, vt);

  attn_k<<<dim3(32, 8), 512, 0, stream>>>(qkv, vt, aout);

  gemm_bt_k<0><<<dim3(2048 / 128, 4096 / 128), 256, 0, stream>>>(aout, Wot, out, 4096, 2048, 2048);
}

// Round 8
// 279.197 us; speedup vs baseline: 1.9738x; 1.0401x over previous
//
#include <hip/hip_runtime.h>
#include <math.h>

#define BB   2
#define LL   2048
#define HIDD 2048
#define NHH  16
#define HDD  128
#define QKVN 6144   // 3*HIDD
#define THR2 11.5416f  // defer-max threshold, log2 domain (= 8 nats)

typedef unsigned short u16;
typedef float  f32x4 __attribute__((ext_vector_type(4)));
typedef __bf16 bf16x8 __attribute__((ext_vector_type(8)));

static __device__ __forceinline__ float exp2_fast(float x){
  return __builtin_amdgcn_exp2f(x);    // v_exp_f32 (native 2^x)
}
static __device__ __forceinline__ u16 f2bf(float x){
  unsigned u = __float_as_uint(x);
  return (u16)((u + 0x7fffu + ((u >> 16) & 1u)) >> 16);
}
static __device__ __forceinline__ float bf2f(u16 b){
  return __uint_as_float(((unsigned)b) << 16);
}
static __device__ __forceinline__ void gl_lds16(const void* g, void* l){
  __builtin_amdgcn_global_load_lds(
      (__attribute__((address_space(1))) void*)(void*)g,
      (__attribute__((address_space(3))) void*)l,
      16, 0, 0);
}

// ---------------- prep kernels ----------------

__global__ void cvt_f32_bf16_k(const float* __restrict__ src, u16* __restrict__ dst, int n4){
  int i = blockIdx.x * blockDim.x + threadIdx.x;
  if (i >= n4) return;
  float4 v = ((const float4*)src)[i];
  ushort4 o;
  o.x = f2bf(v.x); o.y = f2bf(v.y); o.z = f2bf(v.z); o.w = f2bf(v.w);
  ((ushort4*)dst)[i] = o;
}

// src: R x C f32 (row-major) -> dst: C x R bf16
__global__ void transpose_cvt_k(const float* __restrict__ src, u16* __restrict__ dst, int R, int C){
  __shared__ float t[32][33];
  int c0 = blockIdx.x * 32, r0 = blockIdx.y * 32;
  int tx = threadIdx.x, ty = threadIdx.y;
  #pragma unroll
  for (int i = 0; i < 32; i += 8) t[ty + i][tx] = src[(size_t)(r0 + ty + i) * C + c0 + tx];
  __syncthreads();
  #pragma unroll
  for (int i = 0; i < 32; i += 8) dst[(size_t)(c0 + ty + i) * R + r0 + tx] = f2bf(t[tx][ty + i]);
}

// in-place RoPE on q,k sections of qkv (bf16). idx over B*L*NH*64
// Q additionally pre-scaled by 1/sqrt(128)*log2(e) -> scores in exp2 domain.
__global__ void rope_k(u16* __restrict__ qkv){
  int idx = blockIdx.x * blockDim.x + threadIdx.x;
  int d   = idx & 63;
  int h   = (idx >> 6) & 15;
  int row = idx >> 10;           // b*L + l
  int l   = row & (LL - 1);
  float fr = __expf(-(float)d * 0.17988946f);   // ln(1e5)/64
  float th = (float)l * 0.25f * fr;             // pos/ROPE_SCALE * freq
  float s, c;
  sincosf(th, &s, &c);
  size_t base = (size_t)row * QKVN + h * HDD + d;
  #pragma unroll
  for (int part = 0; part < 2; part++){         // q then k
    float f = (part == 0) ? 0.12753375f : 1.0f; // scale*log2e folded into Q
    float x1 = bf2f(qkv[base]), x2 = bf2f(qkv[base + 64]);
    qkv[base]      = f2bf((x1 * c - x2 * s) * f);
    qkv[base + 64] = f2bf((x1 * s + x2 * c) * f);
    base += HIDD;
  }
}

// v section of qkv -> vt[(b,h), d, l]
__global__ void build_vt_k(const u16* __restrict__ qkv, u16* __restrict__ vt){
  __shared__ u16 t[32][33];
  int bh = blockIdx.z;
  int b = bh >> 4, h = bh & 15;
  const u16* src = qkv + (size_t)b * LL * QKVN + 2 * HIDD + h * HDD; // [l][d] stride QKVN
  u16* dst = vt + (size_t)bh * HDD * LL;                              // [d][l] stride LL
  int d0 = blockIdx.x * 32, l0 = blockIdx.y * 32;
  int tx = threadIdx.x, ty = threadIdx.y;
  #pragma unroll
  for (int i = 0; i < 32; i += 8) t[ty + i][tx] = src[(size_t)(l0 + ty + i) * QKVN + d0 + tx];
  __syncthreads();
  #pragma unroll
  for (int i = 0; i < 32; i += 8) dst[(size_t)(d0 + ty + i) * LL + l0 + tx] = t[tx][ty + i];
}

// ---------------- GEMM v2: C[M,N] = A[M,K] * Bt[N,K]^T ----------------
// BM=128, BN=256, BK=64, 8 waves (512 thr), per-wave 64x64 (4x4 16x16-frags).
// Double-buffered LDS (96KB), counted-vmcnt pipeline (T3+T4): prefetch 2 tiles
// deep, never drain vmcnt to 0 in the loop, raw s_barriers (no implicit drain).
// LDS XOR-swizzle ((r&7)<<4 on 16B granules) via pre-swizzled global source.

#define G2_STAGE(kt, bsel) do {                                                           \
  _Pragma("unroll")                                                                       \
  for (int i_ = 0; i_ < 2; i_++){     /* A: 128x64 = 1024 chunks */                       \
    int c_ = ((i_ * 8 + wv) * 64) + lane;                                                 \
    int p_ = c_ * 16;                                                                     \
    int r_ = p_ >> 7; int cb_ = (p_ & 127) ^ ((r_ & 7) << 4);                             \
    gl_lds16(A + (size_t)(m0 + r_) * K + (kt) + (cb_ >> 1),                               \
             &AB[bsel][((i_ * 8 + wv) * 64) * 8]);                                        \
  }                                                                                       \
  _Pragma("unroll")                                                                       \
  for (int i_ = 0; i_ < 4; i_++){     /* B: 256x64 = 2048 chunks */                       \
    int c_ = ((i_ * 8 + wv) * 64) + lane;                                                 \
    int p_ = c_ * 16;                                                                     \
    int r_ = p_ >> 7; int cb_ = (p_ & 127) ^ ((r_ & 7) << 4);                             \
    gl_lds16(Bt + (size_t)(n0 + r_) * K + (kt) + (cb_ >> 1),                              \
             &AB[bsel][8192 + ((i_ * 8 + wv) * 64) * 8]);                                 \
  }                                                                                       \
} while(0)

template<int OUT_BF16>
__global__ __launch_bounds__(512, 1) void gemm_bt2_k(
    const u16* __restrict__ A, const u16* __restrict__ Bt,
    void* __restrict__ Cout, int M, int N, int K)
{
  __shared__ __align__(16) u16 AB[2][24576];   // per buf: A[128][64] @0, B[256][64] @8192
  const int tid = threadIdx.x, lane = tid & 63, wv = tid >> 6;
  const int wr = wv >> 2, wc = wv & 3;          // 2 (M) x 4 (N) waves
  const int m0 = blockIdx.y * 128, n0 = blockIdx.x * 256;
  const int rq = lane >> 4, cl = lane & 15;
  const int NT = K >> 6;                        // 64-wide K tiles

  const f32x4 Z = {0.f, 0.f, 0.f, 0.f};
  f32x4 acc[4][4];
  #pragma unroll
  for (int m = 0; m < 4; m++)
    #pragma unroll
    for (int n = 0; n < 4; n++) acc[m][n] = Z;

  // prologue: stage tiles 0 and 1; wait only for tile 0 (6 loads of tile 1 in flight)
  G2_STAGE(0, 0);
  G2_STAGE(64, 1);
  asm volatile("s_waitcnt vmcnt(6)");
  __builtin_amdgcn_sched_barrier(0);
  __builtin_amdgcn_s_barrier();

  int cur = 0;
  for (int t = 0; t < NT; t++){
    const char* As_ = (const char*)&AB[cur][0];
    const char* Bs_ = (const char*)&AB[cur][8192];

    #pragma unroll
    for (int ks = 0; ks < 2; ks++){
      const int kb = ks * 64 + rq * 16;
      bf16x8 a[4], b[4];
      #pragma unroll
      for (int m = 0; m < 4; m++){
        int r = wr * 64 + m * 16 + cl;
        a[m] = *(const bf16x8*)(As_ + r * 128 + (kb ^ ((r & 7) << 4)));
      }
      #pragma unroll
      for (int n = 0; n < 4; n++){
        int r = wc * 64 + n * 16 + cl;
        b[n] = *(const bf16x8*)(Bs_ + r * 128 + (kb ^ ((r & 7) << 4)));
      }
      __builtin_amdgcn_s_setprio(1);
      #pragma unroll
      for (int m = 0; m < 4; m++)
        #pragma unroll
        for (int n = 0; n < 4; n++)
          acc[m][n] = __builtin_amdgcn_mfma_f32_16x16x32_bf16(a[m], b[n], acc[m][n], 0, 0, 0);
      __builtin_amdgcn_s_setprio(0);
    }

    // all my ds_reads of buf[cur] are pinned above this point
    __builtin_amdgcn_sched_barrier(0);
    __builtin_amdgcn_s_barrier();              // every wave done READING buf[cur]

    if (t + 2 < NT){
      G2_STAGE((t + 2) * 64, cur);             // overwrite freed buffer
      asm volatile("s_waitcnt vmcnt(6)");      // tile t+1 landed; t+2 stays in flight
    } else {
      asm volatile("s_waitcnt vmcnt(0)");      // tail: drain remaining
    }
    __builtin_amdgcn_sched_barrier(0);
    __builtin_amdgcn_s_barrier();              // every wave's tile t+1 landed
    cur ^= 1;
  }

  #pragma unroll
  for (int m = 0; m < 4; m++){
    int gr0 = m0 + wr * 64 + m * 16 + rq * 4;
    #pragma unroll
    for (int n = 0; n < 4; n++){
      int gc = n0 + wc * 64 + n * 16 + cl;
      #pragma unroll
      for (int rr = 0; rr < 4; rr++){
        if (OUT_BF16) ((u16*)Cout)[(size_t)(gr0 + rr) * N + gc] = f2bf(acc[m][n][rr]);
        else          ((float*)Cout)[(size_t)(gr0 + rr) * N + gc] = acc[m][n][rr];
      }
    }
  }
}

// ---------------- flash attention: paired q-tiles, uniform blocks ----------------
// grid (bh=32 fast, pair p=0..7), 512 threads = 8 waves x 16 q-rows.
// Block processes q-tile (15-p) then q-tile p: exactly 34 tile-iters per block.
// K double-buffered, V single-buffered, P overlays the consumed K buffer.

#define STAGE_K(jj, bsel) do {                                                            \
  _Pragma("unroll")                                                                       \
  for (int i_ = 0; i_ < 2; i_++){                                                         \
    int fb_ = (i_ * 8 + wv) * 64;                                                         \
    int p_  = (fb_ + lane) * 16;                                                          \
    int r_ = p_ >> 8; int cb_ = (p_ & 255) ^ ((r_ & 7) << 4);                             \
    gl_lds16(qkv + (size_t)(b * LL + (jj) * 64 + r_) * QKVN + HIDD + h * HDD + (cb_ >> 1),\
             &Kb[bsel][fb_ * 8]);                                                         \
  }                                                                                       \
} while(0)

#define STAGE_V(jj) do {                                                                  \
  _Pragma("unroll")                                                                       \
  for (int i_ = 0; i_ < 2; i_++){                                                         \
    int fb_ = (i_ * 8 + wv) * 64;                                                         \
    int p_  = (fb_ + lane) * 16;                                                          \
    int r_ = p_ >> 7; int cb_ = (p_ & 127) ^ ((r_ & 7) << 4);                             \
    gl_lds16(vt + (size_t)(bh * HDD + r_) * LL + (jj) * 64 + (cb_ >> 1), &Vs[fb_ * 8]);   \
  }                                                                                       \
} while(0)

__global__ __launch_bounds__(512, 1) void attn_k(
    const u16* __restrict__ qkv, const u16* __restrict__ vt,
    u16* __restrict__ aout)
{
  __shared__ __align__(16) u16 Kb[2][64 * 128];   // K tiles [64][128], 2x16KB
  __shared__ __align__(16) u16 Vs[128 * 64];      // V^T tile [128][64], 16KB
  const int tid = threadIdx.x, lane = tid & 63, wv = tid >> 6;
  const int bh = blockIdx.x;                      // fast dim -> XCD = bh % 8
  const int pr = blockIdx.y;                      // pair index 0..7
  const int b = bh >> 4, h = bh & 15;
  const int rq = lane >> 4, cl = lane & 15;

  bf16x8 ones;
  #pragma unroll
  for (int i = 0; i < 8; i++) ones[i] = (__bf16)1.0f;
  const f32x4 Z = {0.f, 0.f, 0.f, 0.f};

  int cur = 0;
  STAGE_K(0, 0);                                  // phase-A tile 0

  #pragma unroll
  for (int ph = 0; ph < 2; ph++){
    const int qt = ph ? pr : (15 - pr);
    const int nj = 2 * qt + 2;

    // Q fragments for this q-tile: wave rows qt*128 + wv*16 + cl
    bf16x8 qf[4];
    {
      const u16* qb = qkv + (size_t)(b * LL + qt * 128 + wv * 16 + cl) * QKVN + h * HDD + rq * 8;
      #pragma unroll
      for (int ks = 0; ks < 4; ks++) qf[ks] = *(const bf16x8*)(qb + ks * 32);
    }

    f32x4 acco[8], accl;
    float mst[4];
    #pragma unroll
    for (int n = 0; n < 8; n++) acco[n] = Z;
    accl = Z;
    #pragma unroll
    for (int rr = 0; rr < 4; rr++) mst[rr] = -INFINITY;

    const int wrow_hi = qt * 128 + wv * 16 + 15;

    if (ph == 0) __syncthreads();                 // initial K landed

    for (int j = 0; j < nj; j++){
      // prefetch next K tile (crosses the phase boundary into phase B's j=0)
      if (j + 1 < nj)      STAGE_K(j + 1, cur ^ 1);
      else if (ph == 0)    STAGE_K(0,     cur ^ 1);
      STAGE_V(j);
      const bool act = (j * 64 <= wrow_hi);

      f32x4 sv[4];
      if (act){
        const char* KsC = (const char*)&Kb[cur][0];
        #pragma unroll
        for (int ct = 0; ct < 4; ct++) sv[ct] = Z;
        #pragma unroll
        for (int ks = 0; ks < 4; ks++){
          const int kb = ks * 64 + rq * 16;
          #pragma unroll
          for (int ct = 0; ct < 4; ct++){
            int r = ct * 16 + cl;
            bf16x8 bfr = *(const bf16x8*)(KsC + r * 256 + (kb ^ ((r & 7) << 4)));
            sv[ct] = __builtin_amdgcn_mfma_f32_16x16x32_bf16(qf[ks], bfr, sv[ct], 0, 0, 0);
          }
        }
      }

      __syncthreads();   // QK reads of Kb[cur] done; V (and next K) landed

      if (act){
        char* pbase = (char*)&Kb[cur][0] + wv * 2048;   // P overlays consumed K
        const bool msk = (j >= 2 * qt);

        float p4[4][4], lmx[4];
        #pragma unroll
        for (int rr = 0; rr < 4; rr++) lmx[rr] = -1e30f;
        const int qg = qt * 128 + wv * 16 + rq * 4;
        #pragma unroll
        for (int ct = 0; ct < 4; ct++){
          int col = j * 64 + ct * 16 + cl;
          #pragma unroll
          for (int rr = 0; rr < 4; rr++){
            float v = sv[ct][rr];                 // already log2-domain
            if (msk && col > qg + rr) v = -1e30f;
            p4[ct][rr] = v;
            lmx[rr] = fmaxf(lmx[rr], v);
          }
        }
        // defer-max gate
        float need = -1e30f;
        #pragma unroll
        for (int rr = 0; rr < 4; rr++) need = fmaxf(need, lmx[rr] - mst[rr]);
        if (__any(need > THR2)){
          float mx[4];
          #pragma unroll
          for (int rr = 0; rr < 4; rr++) mx[rr] = lmx[rr];
          #pragma unroll
          for (int off = 1; off < 16; off <<= 1)
            #pragma unroll
            for (int rr = 0; rr < 4; rr++)
              mx[rr] = fmaxf(mx[rr], __shfl_xor(mx[rr], off, 64));
          #pragma unroll
          for (int rr = 0; rr < 4; rr++){
            float mn  = fmaxf(mst[rr], mx[rr]);
            float fsc = exp2_fast(mst[rr] - mn);
            mst[rr] = mn;
            accl[rr] *= fsc;
            #pragma unroll
            for (int n = 0; n < 8; n++) acco[n][rr] *= fsc;
          }
        }
        #pragma unroll
        for (int ct = 0; ct < 4; ct++)
          #pragma unroll
          for (int rr = 0; rr < 4; rr++){
            float e = exp2_fast(p4[ct][rr] - mst[rr]);
            int wr = rq * 4 + rr;
            *(u16*)(pbase + wr * 128 + (((ct * 16 + cl) * 2) ^ ((wr & 7) << 4))) = f2bf(e);
          }

        // O += P V ; l += P 1
        const char* VsC = (const char*)Vs;
        #pragma unroll
        for (int ks = 0; ks < 2; ks++){
          const int kvb = ks * 64 + rq * 16;
          bf16x8 pa = *(const bf16x8*)(pbase + cl * 128 + (kvb ^ ((cl & 7) << 4)));
          accl = __builtin_amdgcn_mfma_f32_16x16x32_bf16(pa, ones, accl, 0, 0, 0);
          #pragma unroll
          for (int n = 0; n < 8; n++){
            int r = n * 16 + cl;
            bf16x8 bfr = *(const bf16x8*)(VsC + r * 128 + (kvb ^ ((r & 7) << 4)));
            acco[n] = __builtin_amdgcn_mfma_f32_16x16x32_bf16(pa, bfr, acco[n], 0, 0, 0);
          }
        }
      }

      __syncthreads();   // Vs + P reads done before next iter's staging
      cur ^= 1;
    }

    // direct write-out
    #pragma unroll
    for (int rr = 0; rr < 4; rr++){
      float inv = 1.0f / accl[rr];
      size_t grow = (size_t)(b * LL + qt * 128 + wv * 16 + rq * 4 + rr);
      #pragma unroll
      for (int n = 0; n < 8; n++)
        aout[grow * HIDD + h * HDD + n * 16 + cl] = f2bf(acco[n][rr] * inv);
    }
  }
}

// ---------------- launcher ----------------

extern "C" void kernel_launch(void* const* d_in, const int* in_sizes, int n_in,
                              void* d_out, int out_size, void* d_ws, size_t ws_size,
                              hipStream_t stream)
{
  const float* x  = (const float*)d_in[0];
  // d_in[1] = mask (causal; applied analytically)
  const float* Wq = (const float*)d_in[2];
  const float* Wk = (const float*)d_in[3];
  const float* Wv = (const float*)d_in[4];
  const float* Wo = (const float*)d_in[5];
  float* out = (float*)d_out;

  if (ws_size < 134217728ull) return;  // need 128 MB of scratch

  char* ws = (char*)d_ws;
  u16* xb   = (u16*)(ws);                  // 4096x2048 bf16  (16 MB)
  u16* Wt   = (u16*)(ws + 16777216ull);    // 6144x2048 bf16  (24 MB) = [Wq|Wk|Wv]^T
  u16* Wot  = (u16*)(ws + 41943040ull);    // 2048x2048 bf16  ( 8 MB)
  u16* qkv  = (u16*)(ws + 50331648ull);    // 4096x6144 bf16  (48 MB)
  u16* vt   = (u16*)(ws + 100663296ull);   // 32x128x2048 bf16(16 MB)
  u16* aout = (u16*)(ws + 117440512ull);   // 4096x2048 bf16  (16 MB)

  cvt_f32_bf16_k<<<2097152 / 256, 256, 0, stream>>>(x, xb, 2097152);
  dim3 tb(32, 8);
  transpose_cvt_k<<<dim3(64, 64), tb, 0, stream>>>(Wq, Wt,                   2048, 2048);
  transpose_cvt_k<<<dim3(64, 64), tb, 0, stream>>>(Wk, Wt + 2048 * 2048,     2048, 2048);
  transpose_cvt_k<<<dim3(64, 64), tb, 0, stream>>>(Wv, Wt + 2 * 2048 * 2048, 2048, 2048);
  transpose_cvt_k<<<dim3(64, 64), tb, 0, stream>>>(Wo, Wot,                  2048, 2048);

  gemm_bt2_k<1><<<dim3(6144 / 256, 4096 / 128), 512, 0, stream>>>(xb, Wt, qkv, 4096, 6144, 2048);
  rope_k<<<4194304 / 256, 256, 0, stream>>>(qkv);
  build_vt_k<<<dim3(4, 64, 32), tb, 0, stream>>>(qkv, vt);

  attn_k<<<dim3(32, 8), 512, 0, stream>>>(qkv, vt, aout);

  gemm_bt2_k<0><<<dim3(2048 / 256, 4096 / 128), 512, 0, stream>>>(aout, Wot, out, 4096, 2048, 2048);
}